// Round 1
// baseline (708.797 us; speedup 1.0000x reference)
//
#include <hip/hip_runtime.h>

// ---------------------------------------------------------------------------
// Triplane sample + 4-layer MLP, N=1e6 points.
//   K0: zero histogram
//   K1: transpose planes [3][32][512][512] f32 -> [3][512][512][32] f16 (x256)
//   K2: convert w0/w1/w2 -> f16
//   K3: Morton-cell histogram (32^3 cells)
//   K4: exclusive scan (single 1024-thread block)
//   K5: scatter points into bucket order: sorted[pos] = {x,y,z,bitcast(idx)}
//   K6: bilinear sample in sorted order -> feats f16 [N][32] (scaled x256)
//   K7: fused MLP (mfma f16, transposed C^T = W.H^T); out[orig_idx] = result
// Scale S=256 keeps f16 in normal range; epilogues add S*b in fp32; final
// layer divides by S in fp32.
//
// R1: mlp_kernel was latency-bound (MfmaUtil 16%, Occupancy 21%) — 68KB LDS
// allowed only 2 blocks/CU. Shrink wave tile 64->32 points (nt=2): LDS/block
// 34816B -> 4 blocks/CU (4 waves/SIMD), acc halves to 64 f32 so VGPR<=128.
// ---------------------------------------------------------------------------

#define SF 256.0f
#define HPAD 136  // halves per point-row in LDS (128 + 8 pad)

typedef _Float16 half8 __attribute__((ext_vector_type(8)));
typedef _Float16 half4_t __attribute__((ext_vector_type(4)));
typedef float f32x4 __attribute__((ext_vector_type(4)));
typedef unsigned int u32x4 __attribute__((ext_vector_type(4)));

// ---------------- K0: zero histogram ----------------
__global__ __launch_bounds__(256) void zero_hist(unsigned* __restrict__ hist) {
  int t = blockIdx.x * 256 + threadIdx.x;
  if (t < 32768) hist[t] = 0u;
}

// ---------------- K1: plane transpose+convert+scale ----------------
__global__ __launch_bounds__(256) void plane_transpose(
    const float* __restrict__ planes, _Float16* __restrict__ ph) {
  int t = blockIdx.x * 256 + threadIdx.x;     // 3*2^18 threads exactly
  int pid = t >> 18;
  int rem = t & ((1 << 18) - 1);              // y*512 + x
  const float* src = planes + ((size_t)pid << 23) + rem;  // [pid][c][y][x]
  union { _Float16 h[32]; u32x4 v[4]; } u;
#pragma unroll
  for (int c = 0; c < 32; c++)
    u.h[c] = (_Float16)(src[(size_t)c << 18] * SF);
  u32x4* dst = reinterpret_cast<u32x4*>(ph + ((size_t)t << 5));
#pragma unroll
  for (int i = 0; i < 4; i++) dst[i] = u.v[i];
}

// ---------------- K2: weight f32 -> f16 ----------------
__global__ __launch_bounds__(256) void weights_convert(
    const float* __restrict__ w0, const float* __restrict__ w1,
    const float* __restrict__ w2, _Float16* __restrict__ w0h,
    _Float16* __restrict__ w1h, _Float16* __restrict__ w2h) {
  int t = blockIdx.x * 256 + threadIdx.x;     // 36864 threads exactly
  if (t < 4096) w0h[t] = (_Float16)w0[t];
  else if (t < 20480) w1h[t - 4096] = (_Float16)w1[t - 4096];
  else w2h[t - 20480] = (_Float16)w2[t - 20480];
}

// ---------------- Morton key ----------------
__device__ inline unsigned spread5(unsigned v) {
  v &= 31u;
  v = (v | (v << 8)) & 0x100Fu;
  v = (v | (v << 4)) & 0x10C3u;
  v = (v | (v << 2)) & 0x1249u;
  return v;
}
__device__ inline unsigned cellkey(float x, float y, float z) {
  int qx = min(31, max(0, (int)((x + 1.0f) * 16.0f)));
  int qy = min(31, max(0, (int)((y + 1.0f) * 16.0f)));
  int qz = min(31, max(0, (int)((z + 1.0f) * 16.0f)));
  return spread5((unsigned)qx) | (spread5((unsigned)qy) << 1) |
         (spread5((unsigned)qz) << 2);
}

// ---------------- K3: histogram ----------------
__global__ __launch_bounds__(256) void hist_kernel(
    const float* __restrict__ coords, unsigned* __restrict__ hist, int npts) {
  int p = blockIdx.x * 256 + threadIdx.x;
  if (p >= npts) return;
  float x = coords[3 * (size_t)p + 0];
  float y = coords[3 * (size_t)p + 1];
  float z = coords[3 * (size_t)p + 2];
  atomicAdd(&hist[cellkey(x, y, z)], 1u);
}

// ---------------- K4: exclusive scan of 32768 counts ----------------
__global__ __launch_bounds__(1024) void scan_kernel(
    const unsigned* __restrict__ hist, unsigned* __restrict__ cursor) {
  __shared__ unsigned sums[1024];
  int t = threadIdx.x;
  unsigned local[32];
  unsigned s = 0;
#pragma unroll
  for (int i = 0; i < 32; i++) { local[i] = hist[t * 32 + i]; s += local[i]; }
  sums[t] = s;
  __syncthreads();
  for (int off = 1; off < 1024; off <<= 1) {
    unsigned v = (t >= off) ? sums[t - off] : 0u;
    __syncthreads();
    sums[t] += v;
    __syncthreads();
  }
  unsigned base = (t == 0) ? 0u : sums[t - 1];
#pragma unroll
  for (int i = 0; i < 32; i++) { cursor[t * 32 + i] = base; base += local[i]; }
}

// ---------------- K5: scatter into bucket order ----------------
__global__ __launch_bounds__(256) void scatter_kernel(
    const float* __restrict__ coords, unsigned* __restrict__ cursor,
    float4* __restrict__ sorted, int npts) {
  int p = blockIdx.x * 256 + threadIdx.x;
  if (p >= npts) return;
  float x = coords[3 * (size_t)p + 0];
  float y = coords[3 * (size_t)p + 1];
  float z = coords[3 * (size_t)p + 2];
  unsigned pos = atomicAdd(&cursor[cellkey(x, y, z)], 1u);
  float4 v;
  v.x = x; v.y = y; v.z = z; v.w = __uint_as_float((unsigned)p);
  sorted[pos] = v;
}

// ---------------- K6: bilinear sampling ----------------
__device__ inline void samp(const _Float16* __restrict__ pl, float X, float Y,
                            float* acc) {
  float fx = (X + 1.0f) * 0.5f * 511.0f;
  float fy = (Y + 1.0f) * 0.5f * 511.0f;
  float x0f = floorf(fx), y0f = floorf(fy);
  float wx1 = fx - x0f, wy1 = fy - y0f;
  float wx0 = 1.0f - wx1, wy0 = 1.0f - wy1;
  int x0 = (int)x0f, y0 = (int)y0f;
  int x1 = x0 + 1, y1 = y0 + 1;
  float vx0 = (x0 >= 0 && x0 < 512) ? 1.0f : 0.0f;
  float vx1 = (x1 >= 0 && x1 < 512) ? 1.0f : 0.0f;
  float vy0 = (y0 >= 0 && y0 < 512) ? 1.0f : 0.0f;
  float vy1 = (y1 >= 0 && y1 < 512) ? 1.0f : 0.0f;
  int xc0 = min(max(x0, 0), 511), xc1 = min(max(x1, 0), 511);
  int yc0 = min(max(y0, 0), 511), yc1 = min(max(y1, 0), 511);
  float w00 = wx0 * wy0 * vx0 * vy0, w10 = wx1 * wy0 * vx1 * vy0;
  float w01 = wx0 * wy1 * vx0 * vy1, w11 = wx1 * wy1 * vx1 * vy1;
  const _Float16* p00 = pl + ((((size_t)yc0 << 9) + xc0) << 5);
  const _Float16* p10 = pl + ((((size_t)yc0 << 9) + xc1) << 5);
  const _Float16* p01 = pl + ((((size_t)yc1 << 9) + xc0) << 5);
  const _Float16* p11 = pl + ((((size_t)yc1 << 9) + xc1) << 5);
#pragma unroll
  for (int ch = 0; ch < 4; ch++) {
    union { u32x4 v; _Float16 h[8]; } a, b, c, d;
    a.v = *reinterpret_cast<const u32x4*>(p00 + ch * 8);
    b.v = *reinterpret_cast<const u32x4*>(p10 + ch * 8);
    c.v = *reinterpret_cast<const u32x4*>(p01 + ch * 8);
    d.v = *reinterpret_cast<const u32x4*>(p11 + ch * 8);
#pragma unroll
    for (int j = 0; j < 8; j++) {
      acc[ch * 8 + j] += w00 * (float)a.h[j] + w10 * (float)b.h[j] +
                         w01 * (float)c.h[j] + w11 * (float)d.h[j];
    }
  }
}

__global__ __launch_bounds__(256) void sample_kernel(
    const float* __restrict__ coords, const float4* __restrict__ sorted,
    const _Float16* __restrict__ ph, _Float16* __restrict__ feats, int npts,
    int use_sorted) {
  // XCD swizzle: give each XCD a contiguous Morton range for L2 locality.
  int nb = gridDim.x, bid = blockIdx.x;
  int per = nb >> 3;
  int sb = (bid < (per << 3)) ? ((bid & 7) * per + (bid >> 3)) : bid;
  int p = sb * 256 + threadIdx.x;
  if (p >= npts) return;
  float cx, cy, cz;
  if (use_sorted) {
    float4 f = sorted[p];
    cx = f.x; cy = f.y; cz = f.z;
  } else {
    cx = coords[3 * (size_t)p + 0];
    cy = coords[3 * (size_t)p + 1];
    cz = coords[3 * (size_t)p + 2];
  }
  float acc[32];
#pragma unroll
  for (int c = 0; c < 32; c++) acc[c] = 0.0f;
  samp(ph, cx, cy, acc);                         // plane 0: (x, y)
  samp(ph + (1u << 23), cy, cz, acc);            // plane 1: (y, z)
  samp(ph + (2u << 23), cx, cz, acc);            // plane 2: (x, z)
  union { _Float16 h[32]; u32x4 v[4]; } u;
#pragma unroll
  for (int c = 0; c < 32; c++) u.h[c] = (_Float16)acc[c];
  u32x4* dst = reinterpret_cast<u32x4*>(feats + ((size_t)p << 5));
#pragma unroll
  for (int i = 0; i < 4; i++) dst[i] = u.v[i];
}

// ---------------- K7: fused MLP ----------------
// 32 points per wave (nt=2), 4 waves/block => 128 pts/block, LDS 34816 B
// => 4 blocks/CU, 16 waves/CU.
__device__ inline half8 ld16(const _Float16* p) {
  return *reinterpret_cast<const half8*>(p);
}

// C^T epilogue: lane holds col=point(lane&15), rows=hidden (quad*4 + r) [m89].
__device__ inline void epilogue(f32x4 (&acc)[8][2], const float* __restrict__ bias,
                                _Float16* H, int n16, int g) {
#pragma unroll
  for (int mt = 0; mt < 8; mt++) {
    f32x4 bb = *reinterpret_cast<const f32x4*>(bias + mt * 16 + g * 4);
#pragma unroll
    for (int nt = 0; nt < 2; nt++) {
      half4_t v;
#pragma unroll
      for (int r = 0; r < 4; r++) {
        float x = acc[mt][nt][r] + SF * bb[r];
        v[r] = (_Float16)fmaxf(x, 0.0f);
      }
      *reinterpret_cast<half4_t*>(&H[(nt * 16 + n16) * HPAD + mt * 16 + g * 4]) = v;
    }
  }
}

__device__ inline void layer128(f32x4 (&acc)[8][2], _Float16* H,
                                const _Float16* __restrict__ Wg,
                                const float* __restrict__ bias, int n16, int g) {
  half8 B[2][4];
#pragma unroll
  for (int nt = 0; nt < 2; nt++)
#pragma unroll
    for (int ks = 0; ks < 4; ks++)
      B[nt][ks] = ld16(&H[(nt * 16 + n16) * HPAD + ks * 32 + g * 8]);
  f32x4 zero = {0.0f, 0.0f, 0.0f, 0.0f};
#pragma unroll
  for (int mt = 0; mt < 8; mt++) {
#pragma unroll
    for (int nt = 0; nt < 2; nt++) acc[mt][nt] = zero;
#pragma unroll
    for (int ks = 0; ks < 4; ks++) {
      half8 A = ld16(Wg + (mt * 16 + n16) * 128 + ks * 32 + g * 8);
#pragma unroll
      for (int nt = 0; nt < 2; nt++)
        acc[mt][nt] =
            __builtin_amdgcn_mfma_f32_16x16x32_f16(A, B[nt][ks], acc[mt][nt], 0, 0, 0);
    }
  }
  epilogue(acc, bias, H, n16, g);
}

__global__ __launch_bounds__(256, 4) void mlp_kernel(
    const _Float16* __restrict__ feats, const float4* __restrict__ sorted,
    const _Float16* __restrict__ w0h, const _Float16* __restrict__ w1h,
    const _Float16* __restrict__ w2h, const float* __restrict__ b0,
    const float* __restrict__ b1, const float* __restrict__ b2,
    const float* __restrict__ w3, const float* __restrict__ b3,
    float* __restrict__ out, int npts, int use_sorted) {
  __shared__ alignas(16) _Float16 hbuf[4][32 * HPAD];  // 34816 B -> 4 blocks/CU
  int tid = threadIdx.x;
  int wv = tid >> 6, lane = tid & 63;
  int n16 = lane & 15, g = lane >> 4;
  long base = (long)blockIdx.x * 128 + wv * 32;  // 32 points per wave
  if (base >= npts) return;                      // no __syncthreads below: safe
  _Float16* H = hbuf[wv];
  f32x4 acc[8][2];

  // layer 0: C^T = W0(128x32) * feats^T(32x32)
  {
    half8 B[2];
#pragma unroll
    for (int nt = 0; nt < 2; nt++)
      B[nt] = ld16(feats + (base + nt * 16 + n16) * 32 + g * 8);
    f32x4 zero = {0.0f, 0.0f, 0.0f, 0.0f};
#pragma unroll
    for (int mt = 0; mt < 8; mt++) {
      half8 A = ld16(w0h + (mt * 16 + n16) * 32 + g * 8);
#pragma unroll
      for (int nt = 0; nt < 2; nt++)
        acc[mt][nt] = __builtin_amdgcn_mfma_f32_16x16x32_f16(A, B[nt], zero, 0, 0, 0);
    }
    epilogue(acc, b0, H, n16, g);
  }

  layer128(acc, H, w1h, b1, n16, g);
  layer128(acc, H, w2h, b2, n16, g);

  // layer 3: out = dot(h2, w3)/S + b3, fp32 VALU.
  // 32 points, 64 lanes: lane = pt + 32*half; each half does 8 of 16 chunks,
  // then reduce across the half pair with shfl_xor(32).
  int pt = lane & 31, half = lane >> 5;
  float o = 0.0f;
#pragma unroll
  for (int ii = 0; ii < 8; ii++) {
    int i = half * 8 + ii;
    half8 hv = ld16(&H[pt * HPAD + i * 8]);
#pragma unroll
    for (int j = 0; j < 8; j++) o += (float)hv[j] * w3[i * 8 + j];
  }
  o += __shfl_xor(o, 32);
  if (lane < 32) {
    unsigned idx = use_sorted ? __float_as_uint(sorted[base + pt].w)
                              : (unsigned)(base + pt);
    out[idx] = o * (1.0f / SF) + b3[0];
  }
}

// ---------------- launch ----------------
extern "C" void kernel_launch(void* const* d_in, const int* in_sizes, int n_in,
                              void* d_out, int out_size, void* d_ws, size_t ws_size,
                              hipStream_t stream) {
  const float* coords = (const float*)d_in[0];
  const float* planes = (const float*)d_in[1];
  const float* w0 = (const float*)d_in[2];
  const float* b0 = (const float*)d_in[3];
  const float* w1 = (const float*)d_in[4];
  const float* b1 = (const float*)d_in[5];
  const float* w2 = (const float*)d_in[6];
  const float* b2 = (const float*)d_in[7];
  const float* w3 = (const float*)d_in[8];
  const float* b3 = (const float*)d_in[9];
  float* out = (float*)d_out;
  int npts = in_sizes[0] / 3;  // 1,000,000

  // workspace layout (bytes):
  //   ph      @ 0          50,331,648
  //   w0h     @ 50331648   8,192
  //   w1h     @ 50339840   32,768
  //   w2h     @ 50372608   32,768
  //   hist    @ 50405376   131,072
  //   cursor  @ 50536448   131,072
  //   sorted  @ 50667520   npts*16
  //   feats   @ 50667520+npts*16   npts*64
  char* ws = (char*)d_ws;
  _Float16* ph = (_Float16*)ws;
  _Float16* w0h = (_Float16*)(ws + 50331648);
  _Float16* w1h = (_Float16*)(ws + 50339840);
  _Float16* w2h = (_Float16*)(ws + 50372608);
  unsigned* hist = (unsigned*)(ws + 50405376);
  unsigned* cursor = (unsigned*)(ws + 50536448);
  float4* sorted = (float4*)(ws + 50667520);
  size_t need = 50667520 + (size_t)npts * 16 + (size_t)npts * 64;
  int use_sorted = (ws_size == 0 || ws_size >= need) ? 1 : 0;
  _Float16* feats = use_sorted
                        ? (_Float16*)(ws + 50667520 + (size_t)npts * 16)
                        : (_Float16*)(ws + 50667520);

  int blk = (npts + 255) / 256;
  int mlp_blk = (npts + 127) / 128;
  plane_transpose<<<3072, 256, 0, stream>>>(planes, ph);
  weights_convert<<<144, 256, 0, stream>>>(w0, w1, w2, w0h, w1h, w2h);
  if (use_sorted) {
    zero_hist<<<128, 256, 0, stream>>>(hist);
    hist_kernel<<<blk, 256, 0, stream>>>(coords, hist, npts);
    scan_kernel<<<1, 1024, 0, stream>>>(hist, cursor);
    scatter_kernel<<<blk, 256, 0, stream>>>(coords, cursor, sorted, npts);
  }
  sample_kernel<<<blk, 256, 0, stream>>>(coords, sorted, ph, feats, npts,
                                         use_sorted);
  mlp_kernel<<<mlp_blk, 256, 0, stream>>>(feats, sorted, w0h, w1h, w2h, b0, b1,
                                          b2, w3, b3, out, npts, use_sorted);
}

// Round 2
// 604.211 us; speedup vs baseline: 1.1731x; 1.1731x over previous
//
#include <hip/hip_runtime.h>

// ---------------------------------------------------------------------------
// Triplane sample + 4-layer MLP, N=1e6 points.
//   K0: zero histogram
//   K1: transpose planes [3][32][512][512] f32 -> [3][512][512][32] f16 (x256)
//   K2: convert w0/w1/w2 -> f16
//   K3: Morton-cell histogram (32^3 cells)
//   K4: exclusive scan (single 1024-thread block)
//   K5: scatter points into bucket order: sorted[pos] = {x,y,z,bitcast(idx)}
//   K6: bilinear sample in sorted order -> feats f16 [N][32] (scaled x256)
//   K7: fused MLP (mfma f16, transposed C^T = W.H^T); out[orig_idx] = result
// Scale S=256 keeps f16 in normal range; epilogues add S*b in fp32; final
// layer divides by S in fp32.
//
// R1 (FAILED, 294us): 32-pt waves halved acc to 64 regs -> compiler dropped to
// 60 VGPR, serialized per-mt, and W traffic doubled. Lesson: keep 64-pt tile.
// R2: pair-split -- two waves share one 64-pt H buffer, splitting the hidden
// (mt) dim: wave w owns rows 64w..64w+63. Per-wave W traffic halves, acc[4][4]
// keeps ILP, LDS/block 34816B -> 4 blocks/CU (4 waves/SIMD). 5 barriers/block;
// tail handled by clamping base (duplicate identical work), no early return.
// ---------------------------------------------------------------------------

#define SF 256.0f
#define HPAD 136  // halves per point-row in LDS (128 + 8 pad)

typedef _Float16 half8 __attribute__((ext_vector_type(8)));
typedef _Float16 half4_t __attribute__((ext_vector_type(4)));
typedef float f32x4 __attribute__((ext_vector_type(4)));
typedef unsigned int u32x4 __attribute__((ext_vector_type(4)));

// ---------------- K0: zero histogram ----------------
__global__ __launch_bounds__(256) void zero_hist(unsigned* __restrict__ hist) {
  int t = blockIdx.x * 256 + threadIdx.x;
  if (t < 32768) hist[t] = 0u;
}

// ---------------- K1: plane transpose+convert+scale ----------------
__global__ __launch_bounds__(256) void plane_transpose(
    const float* __restrict__ planes, _Float16* __restrict__ ph) {
  int t = blockIdx.x * 256 + threadIdx.x;     // 3*2^18 threads exactly
  int pid = t >> 18;
  int rem = t & ((1 << 18) - 1);              // y*512 + x
  const float* src = planes + ((size_t)pid << 23) + rem;  // [pid][c][y][x]
  union { _Float16 h[32]; u32x4 v[4]; } u;
#pragma unroll
  for (int c = 0; c < 32; c++)
    u.h[c] = (_Float16)(src[(size_t)c << 18] * SF);
  u32x4* dst = reinterpret_cast<u32x4*>(ph + ((size_t)t << 5));
#pragma unroll
  for (int i = 0; i < 4; i++) dst[i] = u.v[i];
}

// ---------------- K2: weight f32 -> f16 ----------------
__global__ __launch_bounds__(256) void weights_convert(
    const float* __restrict__ w0, const float* __restrict__ w1,
    const float* __restrict__ w2, _Float16* __restrict__ w0h,
    _Float16* __restrict__ w1h, _Float16* __restrict__ w2h) {
  int t = blockIdx.x * 256 + threadIdx.x;     // 36864 threads exactly
  if (t < 4096) w0h[t] = (_Float16)w0[t];
  else if (t < 20480) w1h[t - 4096] = (_Float16)w1[t - 4096];
  else w2h[t - 20480] = (_Float16)w2[t - 20480];
}

// ---------------- Morton key ----------------
__device__ inline unsigned spread5(unsigned v) {
  v &= 31u;
  v = (v | (v << 8)) & 0x100Fu;
  v = (v | (v << 4)) & 0x10C3u;
  v = (v | (v << 2)) & 0x1249u;
  return v;
}
__device__ inline unsigned cellkey(float x, float y, float z) {
  int qx = min(31, max(0, (int)((x + 1.0f) * 16.0f)));
  int qy = min(31, max(0, (int)((y + 1.0f) * 16.0f)));
  int qz = min(31, max(0, (int)((z + 1.0f) * 16.0f)));
  return spread5((unsigned)qx) | (spread5((unsigned)qy) << 1) |
         (spread5((unsigned)qz) << 2);
}

// ---------------- K3: histogram ----------------
__global__ __launch_bounds__(256) void hist_kernel(
    const float* __restrict__ coords, unsigned* __restrict__ hist, int npts) {
  int p = blockIdx.x * 256 + threadIdx.x;
  if (p >= npts) return;
  float x = coords[3 * (size_t)p + 0];
  float y = coords[3 * (size_t)p + 1];
  float z = coords[3 * (size_t)p + 2];
  atomicAdd(&hist[cellkey(x, y, z)], 1u);
}

// ---------------- K4: exclusive scan of 32768 counts ----------------
__global__ __launch_bounds__(1024) void scan_kernel(
    const unsigned* __restrict__ hist, unsigned* __restrict__ cursor) {
  __shared__ unsigned sums[1024];
  int t = threadIdx.x;
  unsigned local[32];
  unsigned s = 0;
#pragma unroll
  for (int i = 0; i < 32; i++) { local[i] = hist[t * 32 + i]; s += local[i]; }
  sums[t] = s;
  __syncthreads();
  for (int off = 1; off < 1024; off <<= 1) {
    unsigned v = (t >= off) ? sums[t - off] : 0u;
    __syncthreads();
    sums[t] += v;
    __syncthreads();
  }
  unsigned base = (t == 0) ? 0u : sums[t - 1];
#pragma unroll
  for (int i = 0; i < 32; i++) { cursor[t * 32 + i] = base; base += local[i]; }
}

// ---------------- K5: scatter into bucket order ----------------
__global__ __launch_bounds__(256) void scatter_kernel(
    const float* __restrict__ coords, unsigned* __restrict__ cursor,
    float4* __restrict__ sorted, int npts) {
  int p = blockIdx.x * 256 + threadIdx.x;
  if (p >= npts) return;
  float x = coords[3 * (size_t)p + 0];
  float y = coords[3 * (size_t)p + 1];
  float z = coords[3 * (size_t)p + 2];
  unsigned pos = atomicAdd(&cursor[cellkey(x, y, z)], 1u);
  float4 v;
  v.x = x; v.y = y; v.z = z; v.w = __uint_as_float((unsigned)p);
  sorted[pos] = v;
}

// ---------------- K6: bilinear sampling ----------------
__device__ inline void samp(const _Float16* __restrict__ pl, float X, float Y,
                            float* acc) {
  float fx = (X + 1.0f) * 0.5f * 511.0f;
  float fy = (Y + 1.0f) * 0.5f * 511.0f;
  float x0f = floorf(fx), y0f = floorf(fy);
  float wx1 = fx - x0f, wy1 = fy - y0f;
  float wx0 = 1.0f - wx1, wy0 = 1.0f - wy1;
  int x0 = (int)x0f, y0 = (int)y0f;
  int x1 = x0 + 1, y1 = y0 + 1;
  float vx0 = (x0 >= 0 && x0 < 512) ? 1.0f : 0.0f;
  float vx1 = (x1 >= 0 && x1 < 512) ? 1.0f : 0.0f;
  float vy0 = (y0 >= 0 && y0 < 512) ? 1.0f : 0.0f;
  float vy1 = (y1 >= 0 && y1 < 512) ? 1.0f : 0.0f;
  int xc0 = min(max(x0, 0), 511), xc1 = min(max(x1, 0), 511);
  int yc0 = min(max(y0, 0), 511), yc1 = min(max(y1, 0), 511);
  float w00 = wx0 * wy0 * vx0 * vy0, w10 = wx1 * wy0 * vx1 * vy0;
  float w01 = wx0 * wy1 * vx0 * vy1, w11 = wx1 * wy1 * vx1 * vy1;
  const _Float16* p00 = pl + ((((size_t)yc0 << 9) + xc0) << 5);
  const _Float16* p10 = pl + ((((size_t)yc0 << 9) + xc1) << 5);
  const _Float16* p01 = pl + ((((size_t)yc1 << 9) + xc0) << 5);
  const _Float16* p11 = pl + ((((size_t)yc1 << 9) + xc1) << 5);
#pragma unroll
  for (int ch = 0; ch < 4; ch++) {
    union { u32x4 v; _Float16 h[8]; } a, b, c, d;
    a.v = *reinterpret_cast<const u32x4*>(p00 + ch * 8);
    b.v = *reinterpret_cast<const u32x4*>(p10 + ch * 8);
    c.v = *reinterpret_cast<const u32x4*>(p01 + ch * 8);
    d.v = *reinterpret_cast<const u32x4*>(p11 + ch * 8);
#pragma unroll
    for (int j = 0; j < 8; j++) {
      acc[ch * 8 + j] += w00 * (float)a.h[j] + w10 * (float)b.h[j] +
                         w01 * (float)c.h[j] + w11 * (float)d.h[j];
    }
  }
}

__global__ __launch_bounds__(256) void sample_kernel(
    const float* __restrict__ coords, const float4* __restrict__ sorted,
    const _Float16* __restrict__ ph, _Float16* __restrict__ feats, int npts,
    int use_sorted) {
  // XCD swizzle: give each XCD a contiguous Morton range for L2 locality.
  int nb = gridDim.x, bid = blockIdx.x;
  int per = nb >> 3;
  int sb = (bid < (per << 3)) ? ((bid & 7) * per + (bid >> 3)) : bid;
  int p = sb * 256 + threadIdx.x;
  if (p >= npts) return;
  float cx, cy, cz;
  if (use_sorted) {
    float4 f = sorted[p];
    cx = f.x; cy = f.y; cz = f.z;
  } else {
    cx = coords[3 * (size_t)p + 0];
    cy = coords[3 * (size_t)p + 1];
    cz = coords[3 * (size_t)p + 2];
  }
  float acc[32];
#pragma unroll
  for (int c = 0; c < 32; c++) acc[c] = 0.0f;
  samp(ph, cx, cy, acc);                         // plane 0: (x, y)
  samp(ph + (1u << 23), cy, cz, acc);            // plane 1: (y, z)
  samp(ph + (2u << 23), cx, cz, acc);            // plane 2: (x, z)
  union { _Float16 h[32]; u32x4 v[4]; } u;
#pragma unroll
  for (int c = 0; c < 32; c++) u.h[c] = (_Float16)acc[c];
  u32x4* dst = reinterpret_cast<u32x4*>(feats + ((size_t)p << 5));
#pragma unroll
  for (int i = 0; i < 4; i++) dst[i] = u.v[i];
}

// ---------------- K7: fused MLP (pair-split) ----------------
// 2 waves share one 64-pt H buffer; wave w owns hidden rows 64w..64w+63.
// Block = 256 threads = 2 pairs = 128 points; LDS 34816 B -> 4 blocks/CU.
__device__ inline half8 ld16(const _Float16* p) {
  return *reinterpret_cast<const half8*>(p);
}

// C^T epilogue: lane holds col=point(lane&15), rows=hidden (quad*4 + r) [m89].
// Global hidden row = (w*4+mt)*16 + g*4 + r.
__device__ inline void epilogue_pair(f32x4 (&acc)[4][4],
                                     const float* __restrict__ bias,
                                     _Float16* H, int n16, int g, int w) {
#pragma unroll
  for (int mt = 0; mt < 4; mt++) {
    int gm = w * 4 + mt;
    f32x4 bb = *reinterpret_cast<const f32x4*>(bias + gm * 16 + g * 4);
#pragma unroll
    for (int nt = 0; nt < 4; nt++) {
      half4_t v;
#pragma unroll
      for (int r = 0; r < 4; r++) {
        float x = acc[mt][nt][r] + SF * bb[r];
        v[r] = (_Float16)fmaxf(x, 0.0f);
      }
      *reinterpret_cast<half4_t*>(
          &H[(nt * 16 + n16) * HPAD + gm * 16 + g * 4]) = v;
    }
  }
}

__device__ inline void layer_pair(f32x4 (&acc)[4][4], _Float16* H,
                                  const _Float16* __restrict__ Wg,
                                  const float* __restrict__ bias, int n16,
                                  int g, int w) {
  f32x4 zero = {0.0f, 0.0f, 0.0f, 0.0f};
#pragma unroll
  for (int mt = 0; mt < 4; mt++)
#pragma unroll
    for (int nt = 0; nt < 4; nt++) acc[mt][nt] = zero;
#pragma unroll
  for (int ks = 0; ks < 4; ks++) {
    half8 B[4];
#pragma unroll
    for (int nt = 0; nt < 4; nt++)
      B[nt] = ld16(&H[(nt * 16 + n16) * HPAD + ks * 32 + g * 8]);
#pragma unroll
    for (int mt = 0; mt < 4; mt++) {
      half8 A = ld16(Wg + ((w * 4 + mt) * 16 + n16) * 128 + ks * 32 + g * 8);
#pragma unroll
      for (int nt = 0; nt < 4; nt++)
        acc[mt][nt] = __builtin_amdgcn_mfma_f32_16x16x32_f16(A, B[nt],
                                                             acc[mt][nt], 0, 0, 0);
    }
  }
  __syncthreads();  // all B reads of H done (both waves) before overwrite
  epilogue_pair(acc, bias, H, n16, g, w);
  __syncthreads();  // H writes visible to partner
}

__global__ __launch_bounds__(256, 4) void mlp_kernel(
    const _Float16* __restrict__ feats, const float4* __restrict__ sorted,
    const _Float16* __restrict__ w0h, const _Float16* __restrict__ w1h,
    const _Float16* __restrict__ w2h, const float* __restrict__ b0,
    const float* __restrict__ b1, const float* __restrict__ b2,
    const float* __restrict__ w3, const float* __restrict__ b3,
    float* __restrict__ out, int npts, int use_sorted) {
  __shared__ alignas(16) _Float16 hbuf[2][64 * HPAD];  // 34816 B -> 4 blk/CU
  int tid = threadIdx.x;
  int wv = tid >> 6, lane = tid & 63;
  int pair = wv >> 1, w = wv & 1;
  int n16 = lane & 15, g = lane >> 4;
  long base = (long)blockIdx.x * 128 + pair * 64;  // 64 points per pair
  if (base + 64 > npts) base = npts - 64;  // tail: duplicate identical work
  _Float16* H = hbuf[pair];
  f32x4 acc[4][4];

  // layer 0: C^T = W0(rows 64w..64w+63, x32) * feats^T(32x64)
  {
    half8 B[4];
#pragma unroll
    for (int nt = 0; nt < 4; nt++)
      B[nt] = ld16(feats + (base + nt * 16 + n16) * 32 + g * 8);
    f32x4 zero = {0.0f, 0.0f, 0.0f, 0.0f};
#pragma unroll
    for (int mt = 0; mt < 4; mt++) {
      half8 A = ld16(w0h + ((w * 4 + mt) * 16 + n16) * 32 + g * 8);
#pragma unroll
      for (int nt = 0; nt < 4; nt++)
        acc[mt][nt] =
            __builtin_amdgcn_mfma_f32_16x16x32_f16(A, B[nt], zero, 0, 0, 0);
    }
    epilogue_pair(acc, b0, H, n16, g, w);
    __syncthreads();  // H(L0) visible before L1 reads
  }

  layer_pair(acc, H, w1h, b1, n16, g, w);
  layer_pair(acc, H, w2h, b2, n16, g, w);

  // layer 3: out = dot(h2, w3)/S + b3, fp32 VALU.
  // Pair covers 64 pts; wave w takes pts w*32..w*32+31. lane = pt' + 32*half,
  // each half does 8 of 16 chunks, then reduce across halves via shfl_xor(32).
  int ptl = lane & 31, hh = lane >> 5;
  int pt = w * 32 + ptl;
  float o = 0.0f;
#pragma unroll
  for (int ii = 0; ii < 8; ii++) {
    int i = hh * 8 + ii;
    half8 hv = ld16(&H[pt * HPAD + i * 8]);
#pragma unroll
    for (int j = 0; j < 8; j++) o += (float)hv[j] * w3[i * 8 + j];
  }
  o += __shfl_xor(o, 32);
  if (lane < 32) {
    unsigned idx = use_sorted ? __float_as_uint(sorted[base + pt].w)
                              : (unsigned)(base + pt);
    out[idx] = o * (1.0f / SF) + b3[0];
  }
}

// ---------------- launch ----------------
extern "C" void kernel_launch(void* const* d_in, const int* in_sizes, int n_in,
                              void* d_out, int out_size, void* d_ws, size_t ws_size,
                              hipStream_t stream) {
  const float* coords = (const float*)d_in[0];
  const float* planes = (const float*)d_in[1];
  const float* w0 = (const float*)d_in[2];
  const float* b0 = (const float*)d_in[3];
  const float* w1 = (const float*)d_in[4];
  const float* b1 = (const float*)d_in[5];
  const float* w2 = (const float*)d_in[6];
  const float* b2 = (const float*)d_in[7];
  const float* w3 = (const float*)d_in[8];
  const float* b3 = (const float*)d_in[9];
  float* out = (float*)d_out;
  int npts = in_sizes[0] / 3;  // 1,000,000

  // workspace layout (bytes):
  //   ph      @ 0          50,331,648
  //   w0h     @ 50331648   8,192
  //   w1h     @ 50339840   32,768
  //   w2h     @ 50372608   32,768
  //   hist    @ 50405376   131,072
  //   cursor  @ 50536448   131,072
  //   sorted  @ 50667520   npts*16
  //   feats   @ 50667520+npts*16   npts*64
  char* ws = (char*)d_ws;
  _Float16* ph = (_Float16*)ws;
  _Float16* w0h = (_Float16*)(ws + 50331648);
  _Float16* w1h = (_Float16*)(ws + 50339840);
  _Float16* w2h = (_Float16*)(ws + 50372608);
  unsigned* hist = (unsigned*)(ws + 50405376);
  unsigned* cursor = (unsigned*)(ws + 50536448);
  float4* sorted = (float4*)(ws + 50667520);
  size_t need = 50667520 + (size_t)npts * 16 + (size_t)npts * 64;
  int use_sorted = (ws_size == 0 || ws_size >= need) ? 1 : 0;
  _Float16* feats = use_sorted
                        ? (_Float16*)(ws + 50667520 + (size_t)npts * 16)
                        : (_Float16*)(ws + 50667520);

  int blk = (npts + 255) / 256;
  int mlp_blk = (npts + 127) / 128;  // 128 pts per block (2 pairs)
  plane_transpose<<<3072, 256, 0, stream>>>(planes, ph);
  weights_convert<<<144, 256, 0, stream>>>(w0, w1, w2, w0h, w1h, w2h);
  if (use_sorted) {
    zero_hist<<<128, 256, 0, stream>>>(hist);
    hist_kernel<<<blk, 256, 0, stream>>>(coords, hist, npts);
    scan_kernel<<<1, 1024, 0, stream>>>(hist, cursor);
    scatter_kernel<<<blk, 256, 0, stream>>>(coords, cursor, sorted, npts);
  }
  sample_kernel<<<blk, 256, 0, stream>>>(coords, sorted, ph, feats, npts,
                                         use_sorted);
  mlp_kernel<<<mlp_blk, 256, 0, stream>>>(feats, sorted, w0h, w1h, w2h, b0, b1,
                                          b2, w3, b3, out, npts, use_sorted);
}

// Round 3
// 598.457 us; speedup vs baseline: 1.1844x; 1.0096x over previous
//
#include <hip/hip_runtime.h>

// ---------------------------------------------------------------------------
// Triplane sample + 4-layer MLP, N=1e6 points.
//   K0: zero histogram
//   K1: transpose planes [3][32][512][512] f32 -> [3][512][512][32] f16 (x256)
//   K2: convert w0/w1/w2 -> f16
//   K3: Morton-cell histogram (32^3 cells)
//   K4: exclusive scan (single 1024-thread block)
//   K5: scatter points into bucket order: sorted[pos] = {x,y,z,bitcast(idx)}
//   K6: bilinear sample in sorted order -> feats f16 [N][32] (scaled x256)
//   K7: fused MLP (mfma f16, transposed C^T = W.H^T); out[orig_idx] = result
// Scale S=256 keeps f16 in normal range; epilogues add S*b in fp32; final
// layer divides by S in fp32.
//
// R1 (FAILED, 294us): 32-pt waves -> ILP collapse + 2x W traffic.
// R2 (NEUTRAL, 184us): pair-split doubled occupancy, dur unchanged. Counters
//   showed WRITE_SIZE 70MB (out is only 4MB) + VGPR=64 < live set: the acc
//   array passed by reference spilled to scratch; kernel was scratch-latency
//   bound all along (~14.5K cy/wave vs ~1.5K of issue work).
// R3: de-spill. Same pair-split geometry, but layer body is a macro (no call
//   boundary), B fully preloaded (64 VGPR), per-mt fused epilogue so acc is
//   16 VGPR recycled 4x. Peak live ~105 < 128 cap of (256,4). No spill.
// ---------------------------------------------------------------------------

#define SF 256.0f
#define HPAD 136  // halves per point-row in LDS (128 + 8 pad)

typedef _Float16 half8 __attribute__((ext_vector_type(8)));
typedef _Float16 half4_t __attribute__((ext_vector_type(4)));
typedef float f32x4 __attribute__((ext_vector_type(4)));
typedef unsigned int u32x4 __attribute__((ext_vector_type(4)));

// ---------------- K0: zero histogram ----------------
__global__ __launch_bounds__(256) void zero_hist(unsigned* __restrict__ hist) {
  int t = blockIdx.x * 256 + threadIdx.x;
  if (t < 32768) hist[t] = 0u;
}

// ---------------- K1: plane transpose+convert+scale ----------------
__global__ __launch_bounds__(256) void plane_transpose(
    const float* __restrict__ planes, _Float16* __restrict__ ph) {
  int t = blockIdx.x * 256 + threadIdx.x;     // 3*2^18 threads exactly
  int pid = t >> 18;
  int rem = t & ((1 << 18) - 1);              // y*512 + x
  const float* src = planes + ((size_t)pid << 23) + rem;  // [pid][c][y][x]
  union { _Float16 h[32]; u32x4 v[4]; } u;
#pragma unroll
  for (int c = 0; c < 32; c++)
    u.h[c] = (_Float16)(src[(size_t)c << 18] * SF);
  u32x4* dst = reinterpret_cast<u32x4*>(ph + ((size_t)t << 5));
#pragma unroll
  for (int i = 0; i < 4; i++) dst[i] = u.v[i];
}

// ---------------- K2: weight f32 -> f16 ----------------
__global__ __launch_bounds__(256) void weights_convert(
    const float* __restrict__ w0, const float* __restrict__ w1,
    const float* __restrict__ w2, _Float16* __restrict__ w0h,
    _Float16* __restrict__ w1h, _Float16* __restrict__ w2h) {
  int t = blockIdx.x * 256 + threadIdx.x;     // 36864 threads exactly
  if (t < 4096) w0h[t] = (_Float16)w0[t];
  else if (t < 20480) w1h[t - 4096] = (_Float16)w1[t - 4096];
  else w2h[t - 20480] = (_Float16)w2[t - 20480];
}

// ---------------- Morton key ----------------
__device__ inline unsigned spread5(unsigned v) {
  v &= 31u;
  v = (v | (v << 8)) & 0x100Fu;
  v = (v | (v << 4)) & 0x10C3u;
  v = (v | (v << 2)) & 0x1249u;
  return v;
}
__device__ inline unsigned cellkey(float x, float y, float z) {
  int qx = min(31, max(0, (int)((x + 1.0f) * 16.0f)));
  int qy = min(31, max(0, (int)((y + 1.0f) * 16.0f)));
  int qz = min(31, max(0, (int)((z + 1.0f) * 16.0f)));
  return spread5((unsigned)qx) | (spread5((unsigned)qy) << 1) |
         (spread5((unsigned)qz) << 2);
}

// ---------------- K3: histogram ----------------
__global__ __launch_bounds__(256) void hist_kernel(
    const float* __restrict__ coords, unsigned* __restrict__ hist, int npts) {
  int p = blockIdx.x * 256 + threadIdx.x;
  if (p >= npts) return;
  float x = coords[3 * (size_t)p + 0];
  float y = coords[3 * (size_t)p + 1];
  float z = coords[3 * (size_t)p + 2];
  atomicAdd(&hist[cellkey(x, y, z)], 1u);
}

// ---------------- K4: exclusive scan of 32768 counts ----------------
__global__ __launch_bounds__(1024) void scan_kernel(
    const unsigned* __restrict__ hist, unsigned* __restrict__ cursor) {
  __shared__ unsigned sums[1024];
  int t = threadIdx.x;
  unsigned local[32];
  unsigned s = 0;
#pragma unroll
  for (int i = 0; i < 32; i++) { local[i] = hist[t * 32 + i]; s += local[i]; }
  sums[t] = s;
  __syncthreads();
  for (int off = 1; off < 1024; off <<= 1) {
    unsigned v = (t >= off) ? sums[t - off] : 0u;
    __syncthreads();
    sums[t] += v;
    __syncthreads();
  }
  unsigned base = (t == 0) ? 0u : sums[t - 1];
#pragma unroll
  for (int i = 0; i < 32; i++) { cursor[t * 32 + i] = base; base += local[i]; }
}

// ---------------- K5: scatter into bucket order ----------------
__global__ __launch_bounds__(256) void scatter_kernel(
    const float* __restrict__ coords, unsigned* __restrict__ cursor,
    float4* __restrict__ sorted, int npts) {
  int p = blockIdx.x * 256 + threadIdx.x;
  if (p >= npts) return;
  float x = coords[3 * (size_t)p + 0];
  float y = coords[3 * (size_t)p + 1];
  float z = coords[3 * (size_t)p + 2];
  unsigned pos = atomicAdd(&cursor[cellkey(x, y, z)], 1u);
  float4 v;
  v.x = x; v.y = y; v.z = z; v.w = __uint_as_float((unsigned)p);
  sorted[pos] = v;
}

// ---------------- K6: bilinear sampling ----------------
__device__ inline void samp(const _Float16* __restrict__ pl, float X, float Y,
                            float* acc) {
  float fx = (X + 1.0f) * 0.5f * 511.0f;
  float fy = (Y + 1.0f) * 0.5f * 511.0f;
  float x0f = floorf(fx), y0f = floorf(fy);
  float wx1 = fx - x0f, wy1 = fy - y0f;
  float wx0 = 1.0f - wx1, wy0 = 1.0f - wy1;
  int x0 = (int)x0f, y0 = (int)y0f;
  int x1 = x0 + 1, y1 = y0 + 1;
  float vx0 = (x0 >= 0 && x0 < 512) ? 1.0f : 0.0f;
  float vx1 = (x1 >= 0 && x1 < 512) ? 1.0f : 0.0f;
  float vy0 = (y0 >= 0 && y0 < 512) ? 1.0f : 0.0f;
  float vy1 = (y1 >= 0 && y1 < 512) ? 1.0f : 0.0f;
  int xc0 = min(max(x0, 0), 511), xc1 = min(max(x1, 0), 511);
  int yc0 = min(max(y0, 0), 511), yc1 = min(max(y1, 0), 511);
  float w00 = wx0 * wy0 * vx0 * vy0, w10 = wx1 * wy0 * vx1 * vy0;
  float w01 = wx0 * wy1 * vx0 * vy1, w11 = wx1 * wy1 * vx1 * vy1;
  const _Float16* p00 = pl + ((((size_t)yc0 << 9) + xc0) << 5);
  const _Float16* p10 = pl + ((((size_t)yc0 << 9) + xc1) << 5);
  const _Float16* p01 = pl + ((((size_t)yc1 << 9) + xc0) << 5);
  const _Float16* p11 = pl + ((((size_t)yc1 << 9) + xc1) << 5);
#pragma unroll
  for (int ch = 0; ch < 4; ch++) {
    union { u32x4 v; _Float16 h[8]; } a, b, c, d;
    a.v = *reinterpret_cast<const u32x4*>(p00 + ch * 8);
    b.v = *reinterpret_cast<const u32x4*>(p10 + ch * 8);
    c.v = *reinterpret_cast<const u32x4*>(p01 + ch * 8);
    d.v = *reinterpret_cast<const u32x4*>(p11 + ch * 8);
#pragma unroll
    for (int j = 0; j < 8; j++) {
      acc[ch * 8 + j] += w00 * (float)a.h[j] + w10 * (float)b.h[j] +
                         w01 * (float)c.h[j] + w11 * (float)d.h[j];
    }
  }
}

__global__ __launch_bounds__(256) void sample_kernel(
    const float* __restrict__ coords, const float4* __restrict__ sorted,
    const _Float16* __restrict__ ph, _Float16* __restrict__ feats, int npts,
    int use_sorted) {
  // XCD swizzle: give each XCD a contiguous Morton range for L2 locality.
  int nb = gridDim.x, bid = blockIdx.x;
  int per = nb >> 3;
  int sb = (bid < (per << 3)) ? ((bid & 7) * per + (bid >> 3)) : bid;
  int p = sb * 256 + threadIdx.x;
  if (p >= npts) return;
  float cx, cy, cz;
  if (use_sorted) {
    float4 f = sorted[p];
    cx = f.x; cy = f.y; cz = f.z;
  } else {
    cx = coords[3 * (size_t)p + 0];
    cy = coords[3 * (size_t)p + 1];
    cz = coords[3 * (size_t)p + 2];
  }
  float acc[32];
#pragma unroll
  for (int c = 0; c < 32; c++) acc[c] = 0.0f;
  samp(ph, cx, cy, acc);                         // plane 0: (x, y)
  samp(ph + (1u << 23), cy, cz, acc);            // plane 1: (y, z)
  samp(ph + (2u << 23), cx, cz, acc);            // plane 2: (x, z)
  union { _Float16 h[32]; u32x4 v[4]; } u;
#pragma unroll
  for (int c = 0; c < 32; c++) u.h[c] = (_Float16)acc[c];
  u32x4* dst = reinterpret_cast<u32x4*>(feats + ((size_t)p << 5));
#pragma unroll
  for (int i = 0; i < 4; i++) dst[i] = u.v[i];
}

// ---------------- K7: fused MLP (pair-split, de-spilled) ----------------
// 2 waves share one 64-pt H buffer; wave w owns hidden rows 64w..64w+63.
// Block = 256 threads = 2 pairs = 128 points; LDS 34816 B -> 4 blocks/CU.
// Layer body is a MACRO (no call boundary -> nothing can force acc to
// scratch). B fully preloaded (64 VGPR); per-mt fused epilogue recycles a
// 16-VGPR accumulator. Peak live ~105 VGPR < 128 cap at (256,4).
__device__ __attribute__((always_inline)) inline half8 ld16(const _Float16* p) {
  return *reinterpret_cast<const half8*>(p);
}

#define LAYER_PAIR(Wg, bias)                                                   \
  {                                                                            \
    half8 Bf[4][4]; /* [nt][ks] : 64 VGPR */                                   \
    _Pragma("unroll") for (int nt = 0; nt < 4; nt++)                           \
    _Pragma("unroll") for (int ks = 0; ks < 4; ks++)                           \
        Bf[nt][ks] = ld16(&H[(nt * 16 + n16) * HPAD + ks * 32 + g * 8]);       \
    __syncthreads(); /* both waves done reading H; safe to overwrite */        \
    _Pragma("unroll") for (int mt = 0; mt < 4; mt++) {                         \
      f32x4 acc[4];                                                            \
      _Pragma("unroll") for (int nt = 0; nt < 4; nt++) acc[nt] = Z4;           \
      _Pragma("unroll") for (int ks = 0; ks < 4; ks++) {                       \
        half8 A = ld16((Wg) + ((w * 4 + mt) * 16 + n16) * 128 + ks * 32 + g * 8); \
        _Pragma("unroll") for (int nt = 0; nt < 4; nt++)                       \
            acc[nt] = __builtin_amdgcn_mfma_f32_16x16x32_f16(A, Bf[nt][ks],    \
                                                             acc[nt], 0, 0, 0); \
      }                                                                        \
      int gm = w * 4 + mt;                                                     \
      f32x4 bb = *reinterpret_cast<const f32x4*>((bias) + gm * 16 + g * 4);    \
      _Pragma("unroll") for (int nt = 0; nt < 4; nt++) {                       \
        half4_t v;                                                             \
        _Pragma("unroll") for (int r = 0; r < 4; r++)                          \
            v[r] = (_Float16)fmaxf(acc[nt][r] + SF * bb[r], 0.0f);             \
        *reinterpret_cast<half4_t*>(                                           \
            &H[(nt * 16 + n16) * HPAD + gm * 16 + g * 4]) = v;                 \
      }                                                                        \
    }                                                                          \
    __syncthreads(); /* H writes visible to partner */                         \
  }

__global__ __launch_bounds__(256, 4) void mlp_kernel(
    const _Float16* __restrict__ feats, const float4* __restrict__ sorted,
    const _Float16* __restrict__ w0h, const _Float16* __restrict__ w1h,
    const _Float16* __restrict__ w2h, const float* __restrict__ b0,
    const float* __restrict__ b1, const float* __restrict__ b2,
    const float* __restrict__ w3, const float* __restrict__ b3,
    float* __restrict__ out, int npts, int use_sorted) {
  __shared__ alignas(16) _Float16 hbuf[2][64 * HPAD];  // 34816 B -> 4 blk/CU
  int tid = threadIdx.x;
  int wv = tid >> 6, lane = tid & 63;
  int pair = wv >> 1, w = wv & 1;
  int n16 = lane & 15, g = lane >> 4;
  long base = (long)blockIdx.x * 128 + pair * 64;  // 64 points per pair
  if (base + 64 > npts) base = npts - 64;  // tail: duplicate identical work
  _Float16* H = hbuf[pair];
  const f32x4 Z4 = {0.0f, 0.0f, 0.0f, 0.0f};

  // layer 0: C^T = W0(rows 64w..64w+63, x32) * feats^T(32x64); K=32 -> 1 ks.
  {
    half8 Bf[4];
#pragma unroll
    for (int nt = 0; nt < 4; nt++)
      Bf[nt] = ld16(feats + (base + nt * 16 + n16) * 32 + g * 8);
#pragma unroll
    for (int mt = 0; mt < 4; mt++) {
      half8 A = ld16(w0h + ((w * 4 + mt) * 16 + n16) * 32 + g * 8);
      f32x4 acc[4];
#pragma unroll
      for (int nt = 0; nt < 4; nt++)
        acc[nt] = __builtin_amdgcn_mfma_f32_16x16x32_f16(A, Bf[nt], Z4, 0, 0, 0);
      int gm = w * 4 + mt;
      f32x4 bb = *reinterpret_cast<const f32x4*>(b0 + gm * 16 + g * 4);
#pragma unroll
      for (int nt = 0; nt < 4; nt++) {
        half4_t v;
#pragma unroll
        for (int r = 0; r < 4; r++)
          v[r] = (_Float16)fmaxf(acc[nt][r] + SF * bb[r], 0.0f);
        *reinterpret_cast<half4_t*>(
            &H[(nt * 16 + n16) * HPAD + gm * 16 + g * 4]) = v;
      }
    }
    __syncthreads();  // H(L0) visible before L1 reads
  }

  LAYER_PAIR(w1h, b1)
  LAYER_PAIR(w2h, b2)

  // layer 3: out = dot(h2, w3)/S + b3, fp32 VALU.
  // Pair covers 64 pts; wave w takes pts w*32..w*32+31. lane = pt' + 32*half,
  // each half does 8 of 16 chunks, then reduce across halves via shfl_xor(32).
  int ptl = lane & 31, hh = lane >> 5;
  int pt = w * 32 + ptl;
  float o = 0.0f;
#pragma unroll
  for (int ii = 0; ii < 8; ii++) {
    int i = hh * 8 + ii;
    half8 hv = ld16(&H[pt * HPAD + i * 8]);
#pragma unroll
    for (int j = 0; j < 8; j++) o += (float)hv[j] * w3[i * 8 + j];
  }
  o += __shfl_xor(o, 32);
  if (lane < 32) {
    unsigned idx = use_sorted ? __float_as_uint(sorted[base + pt].w)
                              : (unsigned)(base + pt);
    out[idx] = o * (1.0f / SF) + b3[0];
  }
}

// ---------------- launch ----------------
extern "C" void kernel_launch(void* const* d_in, const int* in_sizes, int n_in,
                              void* d_out, int out_size, void* d_ws, size_t ws_size,
                              hipStream_t stream) {
  const float* coords = (const float*)d_in[0];
  const float* planes = (const float*)d_in[1];
  const float* w0 = (const float*)d_in[2];
  const float* b0 = (const float*)d_in[3];
  const float* w1 = (const float*)d_in[4];
  const float* b1 = (const float*)d_in[5];
  const float* w2 = (const float*)d_in[6];
  const float* b2 = (const float*)d_in[7];
  const float* w3 = (const float*)d_in[8];
  const float* b3 = (const float*)d_in[9];
  float* out = (float*)d_out;
  int npts = in_sizes[0] / 3;  // 1,000,000

  // workspace layout (bytes):
  //   ph      @ 0          50,331,648
  //   w0h     @ 50331648   8,192
  //   w1h     @ 50339840   32,768
  //   w2h     @ 50372608   32,768
  //   hist    @ 50405376   131,072
  //   cursor  @ 50536448   131,072
  //   sorted  @ 50667520   npts*16
  //   feats   @ 50667520+npts*16   npts*64
  char* ws = (char*)d_ws;
  _Float16* ph = (_Float16*)ws;
  _Float16* w0h = (_Float16*)(ws + 50331648);
  _Float16* w1h = (_Float16*)(ws + 50339840);
  _Float16* w2h = (_Float16*)(ws + 50372608);
  unsigned* hist = (unsigned*)(ws + 50405376);
  unsigned* cursor = (unsigned*)(ws + 50536448);
  float4* sorted = (float4*)(ws + 50667520);
  size_t need = 50667520 + (size_t)npts * 16 + (size_t)npts * 64;
  int use_sorted = (ws_size == 0 || ws_size >= need) ? 1 : 0;
  _Float16* feats = use_sorted
                        ? (_Float16*)(ws + 50667520 + (size_t)npts * 16)
                        : (_Float16*)(ws + 50667520);

  int blk = (npts + 255) / 256;
  int mlp_blk = (npts + 127) / 128;  // 128 pts per block (2 pairs)
  plane_transpose<<<3072, 256, 0, stream>>>(planes, ph);
  weights_convert<<<144, 256, 0, stream>>>(w0, w1, w2, w0h, w1h, w2h);
  if (use_sorted) {
    zero_hist<<<128, 256, 0, stream>>>(hist);
    hist_kernel<<<blk, 256, 0, stream>>>(coords, hist, npts);
    scan_kernel<<<1, 1024, 0, stream>>>(hist, cursor);
    scatter_kernel<<<blk, 256, 0, stream>>>(coords, cursor, sorted, npts);
  }
  sample_kernel<<<blk, 256, 0, stream>>>(coords, sorted, ph, feats, npts,
                                         use_sorted);
  mlp_kernel<<<mlp_blk, 256, 0, stream>>>(feats, sorted, w0h, w1h, w2h, b0, b1,
                                          b2, w3, b3, out, npts, use_sorted);
}

// Round 4
// 508.899 us; speedup vs baseline: 1.3928x; 1.1760x over previous
//
#include <hip/hip_runtime.h>

// ---------------------------------------------------------------------------
// Triplane sample + 4-layer MLP, N=1e6 points.
//   K0: zero histogram
//   K1: transpose planes [3][32][512][512] f32 -> [3][512][512][32] f16 (x256)
//   K2: convert w0/w1/w2 -> f16
//   K3: Morton-cell histogram (32^3 cells)
//   K4: exclusive scan (single 1024-thread block)
//   K5: scatter points into bucket order: sorted[pos] = {x,y,z,bitcast(idx)}
//   K6 (fused): sample 128 pts/block -> LDS feats -> pair-split MFMA MLP
//               -> out[orig_idx].
// Scale S=256 keeps f16 in normal range; epilogues add S*b in fp32; final
// layer divides by S in fp32.
//
// R1 (FAILED, 294us): 32-pt waves -> ILP collapse + 2x W traffic.
// R2 (NEUTRAL): pair-split, 4 blk/CU; spilled via by-ref acc (WRITE 70MB).
// R3 (NEUTRAL, 177us): de-spilled (WRITE back to 36MB = out amplification);
//   dur barely moved -> mlp is latency-chain bound, not occupancy/W/spill.
// R4: fuse sampling into the MLP kernel. Kills the 128MB feats HBM round
//   trip + one dispatch; sampling gathers of one block overlap MFMA of
//   another (4 blk/CU kept: feats overlaid in H LDS, stride 40 halves,
//   16B aligned, bank-uniform). 2 threads/pt sample 16ch each.
// ---------------------------------------------------------------------------

#define SF 256.0f
#define HPAD 136  // halves per point-row in LDS H (128 + 8 pad), 16B aligned
#define FSTR 40   // halves per point-row for LDS feats overlay (32 + 8 pad)

typedef _Float16 half8 __attribute__((ext_vector_type(8)));
typedef _Float16 half4_t __attribute__((ext_vector_type(4)));
typedef float f32x4 __attribute__((ext_vector_type(4)));
typedef unsigned int u32x4 __attribute__((ext_vector_type(4)));

// ---------------- K0: zero histogram ----------------
__global__ __launch_bounds__(256) void zero_hist(unsigned* __restrict__ hist) {
  int t = blockIdx.x * 256 + threadIdx.x;
  if (t < 32768) hist[t] = 0u;
}

// ---------------- K1: plane transpose+convert+scale ----------------
__global__ __launch_bounds__(256) void plane_transpose(
    const float* __restrict__ planes, _Float16* __restrict__ ph) {
  int t = blockIdx.x * 256 + threadIdx.x;     // 3*2^18 threads exactly
  int pid = t >> 18;
  int rem = t & ((1 << 18) - 1);              // y*512 + x
  const float* src = planes + ((size_t)pid << 23) + rem;  // [pid][c][y][x]
  union { _Float16 h[32]; u32x4 v[4]; } u;
#pragma unroll
  for (int c = 0; c < 32; c++)
    u.h[c] = (_Float16)(src[(size_t)c << 18] * SF);
  u32x4* dst = reinterpret_cast<u32x4*>(ph + ((size_t)t << 5));
#pragma unroll
  for (int i = 0; i < 4; i++) dst[i] = u.v[i];
}

// ---------------- K2: weight f32 -> f16 ----------------
__global__ __launch_bounds__(256) void weights_convert(
    const float* __restrict__ w0, const float* __restrict__ w1,
    const float* __restrict__ w2, _Float16* __restrict__ w0h,
    _Float16* __restrict__ w1h, _Float16* __restrict__ w2h) {
  int t = blockIdx.x * 256 + threadIdx.x;     // 36864 threads exactly
  if (t < 4096) w0h[t] = (_Float16)w0[t];
  else if (t < 20480) w1h[t - 4096] = (_Float16)w1[t - 4096];
  else w2h[t - 20480] = (_Float16)w2[t - 20480];
}

// ---------------- Morton key ----------------
__device__ inline unsigned spread5(unsigned v) {
  v &= 31u;
  v = (v | (v << 8)) & 0x100Fu;
  v = (v | (v << 4)) & 0x10C3u;
  v = (v | (v << 2)) & 0x1249u;
  return v;
}
__device__ inline unsigned cellkey(float x, float y, float z) {
  int qx = min(31, max(0, (int)((x + 1.0f) * 16.0f)));
  int qy = min(31, max(0, (int)((y + 1.0f) * 16.0f)));
  int qz = min(31, max(0, (int)((z + 1.0f) * 16.0f)));
  return spread5((unsigned)qx) | (spread5((unsigned)qy) << 1) |
         (spread5((unsigned)qz) << 2);
}

// ---------------- K3: histogram ----------------
__global__ __launch_bounds__(256) void hist_kernel(
    const float* __restrict__ coords, unsigned* __restrict__ hist, int npts) {
  int p = blockIdx.x * 256 + threadIdx.x;
  if (p >= npts) return;
  float x = coords[3 * (size_t)p + 0];
  float y = coords[3 * (size_t)p + 1];
  float z = coords[3 * (size_t)p + 2];
  atomicAdd(&hist[cellkey(x, y, z)], 1u);
}

// ---------------- K4: exclusive scan of 32768 counts ----------------
__global__ __launch_bounds__(1024) void scan_kernel(
    const unsigned* __restrict__ hist, unsigned* __restrict__ cursor) {
  __shared__ unsigned sums[1024];
  int t = threadIdx.x;
  unsigned local[32];
  unsigned s = 0;
#pragma unroll
  for (int i = 0; i < 32; i++) { local[i] = hist[t * 32 + i]; s += local[i]; }
  sums[t] = s;
  __syncthreads();
  for (int off = 1; off < 1024; off <<= 1) {
    unsigned v = (t >= off) ? sums[t - off] : 0u;
    __syncthreads();
    sums[t] += v;
    __syncthreads();
  }
  unsigned base = (t == 0) ? 0u : sums[t - 1];
#pragma unroll
  for (int i = 0; i < 32; i++) { cursor[t * 32 + i] = base; base += local[i]; }
}

// ---------------- K5: scatter into bucket order ----------------
__global__ __launch_bounds__(256) void scatter_kernel(
    const float* __restrict__ coords, unsigned* __restrict__ cursor,
    float4* __restrict__ sorted, int npts) {
  int p = blockIdx.x * 256 + threadIdx.x;
  if (p >= npts) return;
  float x = coords[3 * (size_t)p + 0];
  float y = coords[3 * (size_t)p + 1];
  float z = coords[3 * (size_t)p + 2];
  unsigned pos = atomicAdd(&cursor[cellkey(x, y, z)], 1u);
  float4 v;
  v.x = x; v.y = y; v.z = z; v.w = __uint_as_float((unsigned)p);
  sorted[pos] = v;
}

// ---------------- bilinear sampling: 16 channels (hf selects half) --------
__device__ __attribute__((always_inline)) inline void samp16(
    const _Float16* __restrict__ pl, float X, float Y, int hf, float* acc) {
  float fx = (X + 1.0f) * 0.5f * 511.0f;
  float fy = (Y + 1.0f) * 0.5f * 511.0f;
  float x0f = floorf(fx), y0f = floorf(fy);
  float wx1 = fx - x0f, wy1 = fy - y0f;
  float wx0 = 1.0f - wx1, wy0 = 1.0f - wy1;
  int x0 = (int)x0f, y0 = (int)y0f;
  int x1 = x0 + 1, y1 = y0 + 1;
  float vx0 = (x0 >= 0 && x0 < 512) ? 1.0f : 0.0f;
  float vx1 = (x1 >= 0 && x1 < 512) ? 1.0f : 0.0f;
  float vy0 = (y0 >= 0 && y0 < 512) ? 1.0f : 0.0f;
  float vy1 = (y1 >= 0 && y1 < 512) ? 1.0f : 0.0f;
  int xc0 = min(max(x0, 0), 511), xc1 = min(max(x1, 0), 511);
  int yc0 = min(max(y0, 0), 511), yc1 = min(max(y1, 0), 511);
  float w00 = wx0 * wy0 * vx0 * vy0, w10 = wx1 * wy0 * vx1 * vy0;
  float w01 = wx0 * wy1 * vx0 * vy1, w11 = wx1 * wy1 * vx1 * vy1;
  const _Float16* p00 = pl + ((((size_t)yc0 << 9) + xc0) << 5) + hf * 16;
  const _Float16* p10 = pl + ((((size_t)yc0 << 9) + xc1) << 5) + hf * 16;
  const _Float16* p01 = pl + ((((size_t)yc1 << 9) + xc0) << 5) + hf * 16;
  const _Float16* p11 = pl + ((((size_t)yc1 << 9) + xc1) << 5) + hf * 16;
#pragma unroll
  for (int ch = 0; ch < 2; ch++) {
    union { u32x4 v; _Float16 h[8]; } a, b, c, d;
    a.v = *reinterpret_cast<const u32x4*>(p00 + ch * 8);
    b.v = *reinterpret_cast<const u32x4*>(p10 + ch * 8);
    c.v = *reinterpret_cast<const u32x4*>(p01 + ch * 8);
    d.v = *reinterpret_cast<const u32x4*>(p11 + ch * 8);
#pragma unroll
    for (int j = 0; j < 8; j++) {
      acc[ch * 8 + j] += w00 * (float)a.h[j] + w10 * (float)b.h[j] +
                         w01 * (float)c.h[j] + w11 * (float)d.h[j];
    }
  }
}

// ---------------- K6: fused sample + MLP ----------------
// Block = 256 threads = 2 pairs = 128 points; LDS 34816 B -> 4 blocks/CU.
// Phase 1: 2 threads/pt sample 16ch each -> LDS feats (stride FSTR halves,
//   overlaid at the front of each pair's H area).
// Phase 2: pair-split MLP -- 2 waves share one 64-pt H buffer; wave w owns
//   hidden rows 64w..64w+63. Layer body is a MACRO (no call boundary), B
//   preloaded, per-mt fused epilogue: no spill, peak ~105 VGPR < 128 cap.
__device__ __attribute__((always_inline)) inline half8 ld16(const _Float16* p) {
  return *reinterpret_cast<const half8*>(p);
}

#define LAYER_PAIR(Wg, bias)                                                   \
  {                                                                            \
    half8 Bf[4][4]; /* [nt][ks] : 64 regs */                                   \
    _Pragma("unroll") for (int nt = 0; nt < 4; nt++)                           \
    _Pragma("unroll") for (int ks = 0; ks < 4; ks++)                           \
        Bf[nt][ks] = ld16(&H[(nt * 16 + n16) * HPAD + ks * 32 + g * 8]);       \
    __syncthreads(); /* all H reads done; safe to overwrite */                 \
    _Pragma("unroll") for (int mt = 0; mt < 4; mt++) {                         \
      f32x4 acc[4];                                                            \
      _Pragma("unroll") for (int nt = 0; nt < 4; nt++) acc[nt] = Z4;           \
      _Pragma("unroll") for (int ks = 0; ks < 4; ks++) {                       \
        half8 A = ld16((Wg) + ((w * 4 + mt) * 16 + n16) * 128 + ks * 32 + g * 8); \
        _Pragma("unroll") for (int nt = 0; nt < 4; nt++)                       \
            acc[nt] = __builtin_amdgcn_mfma_f32_16x16x32_f16(A, Bf[nt][ks],    \
                                                             acc[nt], 0, 0, 0); \
      }                                                                        \
      int gm = w * 4 + mt;                                                     \
      f32x4 bb = *reinterpret_cast<const f32x4*>((bias) + gm * 16 + g * 4);    \
      _Pragma("unroll") for (int nt = 0; nt < 4; nt++) {                       \
        half4_t v;                                                             \
        _Pragma("unroll") for (int r = 0; r < 4; r++)                          \
            v[r] = (_Float16)fmaxf(acc[nt][r] + SF * bb[r], 0.0f);             \
        *reinterpret_cast<half4_t*>(                                           \
            &H[(nt * 16 + n16) * HPAD + gm * 16 + g * 4]) = v;                 \
      }                                                                        \
    }                                                                          \
    __syncthreads(); /* H writes visible to partner */                         \
  }

__global__ __launch_bounds__(256, 4) void fused_kernel(
    const float* __restrict__ coords, const float4* __restrict__ sorted,
    const _Float16* __restrict__ ph, const _Float16* __restrict__ w0h,
    const _Float16* __restrict__ w1h, const _Float16* __restrict__ w2h,
    const float* __restrict__ b0, const float* __restrict__ b1,
    const float* __restrict__ b2, const float* __restrict__ w3,
    const float* __restrict__ b3, float* __restrict__ out, int npts,
    int use_sorted) {
  __shared__ alignas(16) _Float16 hbuf[2][64 * HPAD];  // 34816 B -> 4 blk/CU
  int tid = threadIdx.x;
  // XCD swizzle: contiguous Morton range per XCD for plane L2 locality.
  int nb = gridDim.x, bid = blockIdx.x;
  int per = nb >> 3;
  int sb = (bid < (per << 3)) ? ((bid & 7) * per + (bid >> 3)) : bid;

  // ---- phase 1: sample 128 points; 2 threads/pt, 16 channels each ----
  {
    int ptl = tid >> 1, hf = tid & 1;  // waves 0,1 cover pair0; 2,3 pair1
    long pb = (long)sb * 128 + (ptl >> 6) * 64;
    if (pb + 64 > npts) pb = npts - 64;  // tail: duplicate identical work
    long pp = pb + (ptl & 63);
    float cx, cy, cz;
    if (use_sorted) {
      float4 f = sorted[pp];
      cx = f.x; cy = f.y; cz = f.z;
    } else {
      cx = coords[3 * pp + 0];
      cy = coords[3 * pp + 1];
      cz = coords[3 * pp + 2];
    }
    float acc[16];
#pragma unroll
    for (int c = 0; c < 16; c++) acc[c] = 0.0f;
    samp16(ph, cx, cy, hf, acc);                  // plane 0: (x, y)
    samp16(ph + (1u << 23), cy, cz, hf, acc);     // plane 1: (y, z)
    samp16(ph + (2u << 23), cx, cz, hf, acc);     // plane 2: (x, z)
    union { _Float16 h[16]; u32x4 v[2]; } u;
#pragma unroll
    for (int c = 0; c < 16; c++) u.h[c] = (_Float16)acc[c];
    _Float16* F = hbuf[ptl >> 6];
    // feats row stride FSTR=40 halves (80B: 16B-aligned, bank-uniform)
    *reinterpret_cast<u32x4*>(&F[(ptl & 63) * FSTR + hf * 16]) = u.v[0];
    *reinterpret_cast<u32x4*>(&F[(ptl & 63) * FSTR + hf * 16 + 8]) = u.v[1];
  }
  __syncthreads();  // feats visible to all waves

  // ---- phase 2: pair-split MLP ----
  int wv = tid >> 6, lane = tid & 63;
  int pair = wv >> 1, w = wv & 1;
  int n16 = lane & 15, g = lane >> 4;
  long base = (long)sb * 128 + pair * 64;
  if (base + 64 > npts) base = npts - 64;  // same clamp as phase 1
  _Float16* H = hbuf[pair];
  const f32x4 Z4 = {0.0f, 0.0f, 0.0f, 0.0f};

  // layer 0: C^T = W0(rows 64w..64w+63, x32) * feats^T(32x64); K=32.
  {
    half8 Bf[4];
#pragma unroll
    for (int nt = 0; nt < 4; nt++)
      Bf[nt] = ld16(&H[(nt * 16 + n16) * FSTR + g * 8]);  // LDS feats
    __syncthreads();  // feats reads done; epilogue may overwrite region
#pragma unroll
    for (int mt = 0; mt < 4; mt++) {
      half8 A = ld16(w0h + ((w * 4 + mt) * 16 + n16) * 32 + g * 8);
      f32x4 acc[4];
#pragma unroll
      for (int nt = 0; nt < 4; nt++)
        acc[nt] = __builtin_amdgcn_mfma_f32_16x16x32_f16(A, Bf[nt], Z4, 0, 0, 0);
      int gm = w * 4 + mt;
      f32x4 bb = *reinterpret_cast<const f32x4*>(b0 + gm * 16 + g * 4);
#pragma unroll
      for (int nt = 0; nt < 4; nt++) {
        half4_t v;
#pragma unroll
        for (int r = 0; r < 4; r++)
          v[r] = (_Float16)fmaxf(acc[nt][r] + SF * bb[r], 0.0f);
        *reinterpret_cast<half4_t*>(
            &H[(nt * 16 + n16) * HPAD + gm * 16 + g * 4]) = v;
      }
    }
    __syncthreads();  // H(L0) visible before L1 reads
  }

  LAYER_PAIR(w1h, b1)
  LAYER_PAIR(w2h, b2)

  // layer 3: out = dot(h2, w3)/S + b3, fp32 VALU.
  // Pair covers 64 pts; wave w takes pts w*32..+31. lane = pt' + 32*half;
  // each half does 8 of 16 chunks, reduce across halves via shfl_xor(32).
  int ptl3 = lane & 31, hh = lane >> 5;
  int pt = w * 32 + ptl3;
  float o = 0.0f;
#pragma unroll
  for (int ii = 0; ii < 8; ii++) {
    int i = hh * 8 + ii;
    half8 hv = ld16(&H[pt * HPAD + i * 8]);
#pragma unroll
    for (int j = 0; j < 8; j++) o += (float)hv[j] * w3[i * 8 + j];
  }
  o += __shfl_xor(o, 32);
  if (lane < 32) {
    unsigned idx = use_sorted ? __float_as_uint(sorted[base + pt].w)
                              : (unsigned)(base + pt);
    out[idx] = o * (1.0f / SF) + b3[0];
  }
}

// ---------------- launch ----------------
extern "C" void kernel_launch(void* const* d_in, const int* in_sizes, int n_in,
                              void* d_out, int out_size, void* d_ws, size_t ws_size,
                              hipStream_t stream) {
  const float* coords = (const float*)d_in[0];
  const float* planes = (const float*)d_in[1];
  const float* w0 = (const float*)d_in[2];
  const float* b0 = (const float*)d_in[3];
  const float* w1 = (const float*)d_in[4];
  const float* b1 = (const float*)d_in[5];
  const float* w2 = (const float*)d_in[6];
  const float* b2 = (const float*)d_in[7];
  const float* w3 = (const float*)d_in[8];
  const float* b3 = (const float*)d_in[9];
  float* out = (float*)d_out;
  int npts = in_sizes[0] / 3;  // 1,000,000

  // workspace layout (bytes):
  //   ph      @ 0          50,331,648
  //   w0h     @ 50331648   8,192
  //   w1h     @ 50339840   32,768
  //   w2h     @ 50372608   32,768
  //   hist    @ 50405376   131,072
  //   cursor  @ 50536448   131,072
  //   sorted  @ 50667520   npts*16
  char* ws = (char*)d_ws;
  _Float16* ph = (_Float16*)ws;
  _Float16* w0h = (_Float16*)(ws + 50331648);
  _Float16* w1h = (_Float16*)(ws + 50339840);
  _Float16* w2h = (_Float16*)(ws + 50372608);
  unsigned* hist = (unsigned*)(ws + 50405376);
  unsigned* cursor = (unsigned*)(ws + 50536448);
  float4* sorted = (float4*)(ws + 50667520);
  size_t need = 50667520 + (size_t)npts * 16;
  int use_sorted = (ws_size == 0 || ws_size >= need) ? 1 : 0;

  int blk = (npts + 255) / 256;
  int fblk = (npts + 127) / 128;  // 128 pts per block (2 pairs)
  plane_transpose<<<3072, 256, 0, stream>>>(planes, ph);
  weights_convert<<<144, 256, 0, stream>>>(w0, w1, w2, w0h, w1h, w2h);
  if (use_sorted) {
    zero_hist<<<128, 256, 0, stream>>>(hist);
    hist_kernel<<<blk, 256, 0, stream>>>(coords, hist, npts);
    scan_kernel<<<1, 1024, 0, stream>>>(hist, cursor);
    scatter_kernel<<<blk, 256, 0, stream>>>(coords, cursor, sorted, npts);
  }
  fused_kernel<<<fblk, 256, 0, stream>>>(coords, sorted, ph, w0h, w1h, w2h, b0,
                                         b1, b2, w3, b3, out, npts, use_sorted);
}